// Round 9
// baseline (5566.505 us; speedup 1.0000x reference)
//
#include <hip/hip_runtime.h>
#include <hip/hip_bf16.h>
#include <stdint.h>

// Problem constants
#define B_  64
#define S_  512
#define E_  300
#define H_  256
#define T_  (B_*S_)     // 32768 tokens
#define G4H 1024        // 4*H gate rows per direction

using half8  = __attribute__((ext_vector_type(8))) _Float16;
using half4  = __attribute__((ext_vector_type(4))) _Float16;
using float4v = __attribute__((ext_vector_type(4))) float;

__device__ inline float sigm(float x) { return 1.f / (1.f + __expf(-x)); }
__device__ inline float tanhf_(float x) {
  float cx = fminf(fmaxf(x, -15.f), 15.f);
  float e = __expf(2.f * cx);
  return (e - 1.f) / (e + 1.f);
}

// raw barrier: drains LDS only, keeps global loads/stores in flight
// (the gx prefetch and h1bf/pd2 output stores ride across it)
#define BARRIER() asm volatile("s_waitcnt lgkmcnt(0)\n\ts_barrier" ::: "memory")

// Un-rematerializable 16B load (weight residency in VGPRs)
__device__ inline uint4 ldx4_pin(const _Float16* p) {
  uint4 r;
  asm volatile("global_load_dwordx4 %0, %1, off\n\ts_waitcnt vmcnt(0)"
               : "=v"(r) : "v"(p));
  return r;
}

// ---------------------------------------------------------------------------
// Prep kernels (unchanged)
// ---------------------------------------------------------------------------
__global__ __launch_bounds__(256) void k_prep_wih(const float* __restrict__ wf,
    const float* __restrict__ wb, _Float16* __restrict__ Bt,
    int KIN, int KP, int total)
{
  int idx = blockIdx.x * 256 + threadIdx.x;
  if (idx >= total) return;
  int n = idx / KP, k = idx % KP;
  int dd = n >> 10, nn = n & 1023;
  int row = (nn & 3) * 256 + (nn >> 2);
  const float* src = dd ? wb : wf;
  Bt[idx] = (_Float16)(k < KIN ? src[row * KIN + k] : 0.f);
}

__global__ __launch_bounds__(256) void k_prep_whh(const float* __restrict__ wf,
    const float* __restrict__ wb, _Float16* __restrict__ Wr)
{
  int idx = blockIdx.x * 256 + threadIdx.x;     // 0 .. 2*1024*256-1
  int dd = idx >> 18;
  int rem = idx & 262143;
  int n = rem >> 8, k = rem & 255;
  int row = (n & 3) * 256 + (n >> 2);
  Wr[idx] = (_Float16)((dd ? wb : wf)[row * 256 + k]);
}

__global__ void k_prep_bias(const float* __restrict__ bif, const float* __restrict__ bhf,
    const float* __restrict__ bib, const float* __restrict__ bhb, float* __restrict__ bias)
{
  int n = blockIdx.x * 256 + threadIdx.x;       // 0..2047
  int dd = n >> 10, nn = n & 1023;
  int row = (nn & 3) * 256 + (nn >> 2);
  bias[n] = dd ? (bib[row] + bhb[row]) : (bif[row] + bhf[row]);
}

__global__ __launch_bounds__(256) void k_gather(const int* __restrict__ ids,
    const float* __restrict__ emb, _Float16* __restrict__ xbf)
{
  int idx = blockIdx.x * 256 + threadIdx.x;     // T*40 threads, 8 f16 each
  int tt = idx / 40;
  int ch = idx % 40;
  int b = tt & 63, s = tt >> 6;
  int id = ids[b * S_ + s];
  const float* src = emb + (size_t)id * E_ + ch * 8;
  half8 v;
#pragma unroll
  for (int e = 0; e < 8; ++e) {
    int k = ch * 8 + e;
    v[e] = (_Float16)(k < E_ ? src[e] : 0.f);
  }
  *(half8*)(xbf + (size_t)tt * 320 + ch * 8) = v;
}

// ---------------------------------------------------------------------------
// Projection GEMM (unchanged): gx[d][t][b][n'] = A @ Bt^T + bias
// ---------------------------------------------------------------------------
template<int K>
__global__ __launch_bounds__(256) void k_gemm(const _Float16* __restrict__ A,
    const _Float16* __restrict__ Bt, const float* __restrict__ bias,
    _Float16* __restrict__ gx)
{
  __shared__ _Float16 sA[128 * 72];
  __shared__ _Float16 sB[128 * 72];
  const int tid = threadIdx.x;
  const int t0 = blockIdx.y * 128;
  const int n0 = blockIdx.x * 128;
  const int lane = tid & 63, wid = tid >> 6;
  const int l15 = lane & 15, q = lane >> 4;
  const int wm = wid & 1, wn = wid >> 1;

  float4v acc[4][4] = {};

  for (int kt = 0; kt < K / 64; ++kt) {
    __syncthreads();
#pragma unroll
    for (int c = 0; c < 4; ++c) {
      int f = tid * 4 + c;
      int row = f >> 3, seg = f & 7;
      *(half8*)&sA[row * 72 + seg * 8] =
          *(const half8*)(A + (size_t)(t0 + row) * K + kt * 64 + seg * 8);
      *(half8*)&sB[row * 72 + seg * 8] =
          *(const half8*)(Bt + (size_t)(n0 + row) * K + kt * 64 + seg * 8);
    }
    __syncthreads();
#pragma unroll
    for (int kk = 0; kk < 2; ++kk) {
      half8 a[4], b[4];
#pragma unroll
      for (int mt = 0; mt < 4; ++mt)
        a[mt] = *(const half8*)&sA[(wm * 64 + mt * 16 + l15) * 72 + kk * 32 + q * 8];
#pragma unroll
      for (int nt = 0; nt < 4; ++nt)
        b[nt] = *(const half8*)&sB[(wn * 64 + nt * 16 + l15) * 72 + kk * 32 + q * 8];
#pragma unroll
      for (int mt = 0; mt < 4; ++mt)
#pragma unroll
        for (int nt = 0; nt < 4; ++nt)
          acc[mt][nt] = __builtin_amdgcn_mfma_f32_16x16x32_f16(a[mt], b[nt], acc[mt][nt], 0, 0, 0);
    }
  }

#pragma unroll
  for (int mt = 0; mt < 4; ++mt) {
#pragma unroll
    for (int nt = 0; nt < 4; ++nt) {
      int token = t0 + wm * 64 + mt * 16 + q * 4;
      int n = n0 + wn * 64 + nt * 16 + l15;
      float bs = bias[n];
      size_t base = (size_t)(n >> 10) * ((size_t)T_ * G4H) + (size_t)token * G4H + (n & 1023);
#pragma unroll
      for (int r = 0; r < 4; ++r)
        gx[base + (size_t)r * G4H] = (_Float16)(acc[mt][nt][r] + bs);
    }
  }
}

// ---------------------------------------------------------------------------
// Persistent recurrence: SINGLE-BLOCK CHAINS (exchange eliminated).
// r4-r8 established publish->consume D ~ 3500-4000cy as a platform constant
// of any cross-block channel; and phase-interleaving provably can't beat
// C+D. So: one 512-thread block per chain (8 blocks total), the ENTIRE
// direction's W_hh resident per block:
//   - 6/8 of each wave's 128 gate-rows as asm-pinned VGPR fragments
//     (192 VGPR/thread), 2/8 in LDS (128 KB, XOR-swizzled: byte ^=
//     (row&7)<<4 -- breaks the 512B-row-stride 16-way bank conflict, G4).
//   - OPERAND-SWAPPED MFMA: acc = mfma(W, h) [A/B fragments of 16x16x32
//     are lane-layout symmetric, so the same register contents serve].
//     Output (m89 layout: col=lane&15=b, row=q*4+r=gate-in-tile) delivers
//     all 4 gates of cell (wv*32+nt*4+q, b=l15) into acc[nt][0..3] of ONE
//     thread -> epilogue straight from the accumulator, NO preact staging,
//     NO second barrier. gx folds into the MFMA C-init.
//   - h exchange: LDS double-buffer + one lgkm-only barrier (~100cy vs
//     ~3800cy of global-memory D).
// Step = C ~ 2000cy instead of C+D ~ 6000cy.
// ---------------------------------------------------------------------------
template<int LAYER>
__global__ __launch_bounds__(512, 2) void k_rec(const _Float16* __restrict__ gx,
    const _Float16* __restrict__ Wr, _Float16* __restrict__ h1bf,
    float* __restrict__ pd2, const float* __restrict__ w_lin)
{
  extern __shared__ char smem[];
  _Float16* wlds = (_Float16*)smem;                     // [8 wv][2 tile][16 row][256 k] swizzled, 128 KB
  _Float16* hst  = (_Float16*)(smem + 131072);          // [2 buf][16 b][288], 18432 B
  float*    wls  = (float*)(smem + 131072 + 18432);     // [256], 1 KB

  const int tid = threadIdx.x;
  const int cg = blockIdx.x;                  // chain 0..7
  const int d = cg >> 2, g = cg & 3;
  const int wv = tid >> 6, lane = tid & 63;
  const int l15 = lane & 15, q = lane >> 4;
  const int b0g = g * 16;
  const int bglob = b0g + l15;                // this thread's batch row

  // stage w_lin and zero both h buffers
  if (tid < 256) wls[tid] = w_lin[tid];
  for (int i = tid; i < 2 * 16 * 144; i += 512)
    ((uint32_t*)hst)[i] = 0u;

  // ---- weights: wave wv owns gate rows [wv*128, wv*128+128) ----
  // tiles nt 0..5 -> VGPR (asm-pinned); tiles 6..7 -> swizzled LDS
  uint4 wreg[6][8];
#pragma unroll
  for (int nt = 0; nt < 6; ++nt)
#pragma unroll
    for (int kt = 0; kt < 8; ++kt)
      wreg[nt][kt] = ldx4_pin(Wr +
          (size_t)(d * G4H + wv * 128 + nt * 16 + l15) * H_ + kt * 32 + q * 8);

#pragma unroll
  for (int tt = 0; tt < 2; ++tt)
#pragma unroll
    for (int j = 0; j < 8; ++j) {
      int row = wv * 128 + (6 + tt) * 16 + l15;
      uint4 w = *(const uint4*)(Wr + (size_t)(d * G4H + row) * H_ + q * 64 + j * 8);
      int byo = (q * 128 + j * 16) ^ ((l15 & 7) << 4);   // swizzled byte offset in row
      *(uint4*)(wlds + wv * 8192 + tt * 4096 + l15 * 256 + (byo >> 1)) = w;
    }

  float creg[8] = {};                         // c-state: 8 cells/thread
  uint2 gq[8];                                // gx quad (i,f,g,o) per cell, fp16

  // prime gx for t=0
  {
    const int time0 = d ? (S_ - 1) : 0;
    const _Float16* gp = gx + ((size_t)d * T_ + (size_t)time0 * B_ + bglob) * G4H
                           + wv * 128 + q * 4;
#pragma unroll
    for (int nt = 0; nt < 8; ++nt)
      gq[nt] = *(const uint2*)(gp + nt * 16);
  }
  __syncthreads();

  for (int t = 0; t < S_; ++t) {
    const int time = d ? (S_ - 1 - t) : t;
    const int cur = t & 1, nxt = cur ^ 1;

    // acc init = gx (C-input of the MFMA chain; fp32 sum order ~ identical)
    float4v acc[8];
#pragma unroll
    for (int nt = 0; nt < 8; ++nt) {
      half4 hz = __builtin_bit_cast(half4, gq[nt]);
      acc[nt][0] = (float)hz[0];
      acc[nt][1] = (float)hz[1];
      acc[nt][2] = (float)hz[2];
      acc[nt][3] = (float)hz[3];
    }

    // reload gq for t+1 (in-flight across the whole step; consumed next init)
    {
      const int tn = (t + 1 < S_) ? t + 1 : t;
      const int timen = d ? (S_ - 1 - tn) : tn;
      const _Float16* gp = gx + ((size_t)d * T_ + (size_t)timen * B_ + bglob) * G4H
                             + wv * 128 + q * 4;
#pragma unroll
      for (int nt = 0; nt < 8; ++nt)
        gq[nt] = *(const uint2*)(gp + nt * 16);
    }

    // MFMA: pre[gate rows 128][b 16] = W_wv @ h(t)^T  (swapped operands)
#pragma unroll
    for (int kt = 0; kt < 8; ++kt) {
      half8 hf = *(const half8*)(hst + cur * 4608 + l15 * 288 + kt * 32 + q * 8);
      int byr = (kt * 64 + q * 16) ^ ((l15 & 7) << 4);
      half8 w6 = *(const half8*)(wlds + wv * 8192 + l15 * 256 + (byr >> 1));
      half8 w7 = *(const half8*)(wlds + wv * 8192 + 4096 + l15 * 256 + (byr >> 1));
#pragma unroll
      for (int nt = 0; nt < 6; ++nt)
        acc[nt] = __builtin_amdgcn_mfma_f32_16x16x32_f16(
            __builtin_bit_cast(half8, wreg[nt][kt]), hf, acc[nt], 0, 0, 0);
      acc[6] = __builtin_amdgcn_mfma_f32_16x16x32_f16(w6, hf, acc[6], 0, 0, 0);
      acc[7] = __builtin_amdgcn_mfma_f32_16x16x32_f16(w7, hf, acc[7], 0, 0, 0);
    }

    // epilogue straight from acc: thread owns cells wv*32+nt*4+q for b=l15
    float partial = 0.f;
#pragma unroll
    for (int nt = 0; nt < 8; ++nt) {
      const int cell = wv * 32 + nt * 4 + q;
      float cv = sigm(acc[nt][1]) * creg[nt] + sigm(acc[nt][0]) * tanhf_(acc[nt][2]);
      float hv = sigm(acc[nt][3]) * tanhf_(cv);
      creg[nt] = cv;
      _Float16 hf16 = (_Float16)hv;
      hst[nxt * 4608 + l15 * 288 + cell] = hf16;
      if (LAYER == 0)
        h1bf[((size_t)time * B_ + bglob) * 512 + d * H_ + cell] = hf16;
      else
        partial += 0.5f * hv * wls[cell];
    }
    if (LAYER == 1) {
      partial += __shfl_xor(partial, 16);
      partial += __shfl_xor(partial, 32);
      if (q == 0)
        atomicAdd(pd2 + ((size_t)d * B_ + bglob) * S_ + time, partial);
    }

    BARRIER();   // release hst[nxt]; gq loads + output stores ride
  }
}

// scores + masked-MSE loss
__global__ __launch_bounds__(256) void k_final(const float* __restrict__ pd2,
    const float* __restrict__ labels, const int* __restrict__ masks,
    const float* __restrict__ b_lin, float* __restrict__ out)
{
  int b = blockIdx.x;
  int tid = threadIdx.x;
  float bl = b_lin[0];
  float se = 0.f, sm = 0.f;
  for (int s = tid; s < S_; s += 256) {
    float p = pd2[(size_t)b * S_ + s] + pd2[(size_t)(B_ + b) * S_ + s];
    float sc = sigm(p + bl);
    out[b * S_ + s] = sc;
    float m = (float)masks[b * S_ + s];
    float e = sc - labels[b * S_ + s];
    se += e * e * m;
    sm += m;
  }
  for (int off = 1; off < 64; off <<= 1) {
    se += __shfl_xor(se, off);
    sm += __shfl_xor(sm, off);
  }
  __shared__ float rs[4], rm[4];
  int wid = tid >> 6;
  if ((tid & 63) == 0) { rs[wid] = se; rm[wid] = sm; }
  __syncthreads();
  if (tid == 0) {
    float te = 0.f, tm = 0.f;
    for (int w = 0; w < 4; ++w) { te += rs[w]; tm += rm[w]; }
    atomicAdd(out + T_, (te / tm) * (1.f / 64.f));
  }
}

// ---------------------------------------------------------------------------
extern "C" void kernel_launch(void* const* d_in, const int* in_sizes, int n_in,
                              void* d_out, int out_size, void* d_ws, size_t ws_size,
                              hipStream_t stream)
{
  (void)in_sizes; (void)n_in; (void)out_size; (void)ws_size;
  const int*   ids    = (const int*)d_in[0];
  const float* labels = (const float*)d_in[1];
  const int*   masks  = (const int*)d_in[2];
  const float* emb    = (const float*)d_in[3];
  const float* w_ih_0f = (const float*)d_in[4];
  const float* w_hh_0f = (const float*)d_in[5];
  const float* b_ih_0f = (const float*)d_in[6];
  const float* b_hh_0f = (const float*)d_in[7];
  const float* w_ih_0b = (const float*)d_in[8];
  const float* w_hh_0b = (const float*)d_in[9];
  const float* b_ih_0b = (const float*)d_in[10];
  const float* b_hh_0b = (const float*)d_in[11];
  const float* w_ih_1f = (const float*)d_in[12];
  const float* w_hh_1f = (const float*)d_in[13];
  const float* b_ih_1f = (const float*)d_in[14];
  const float* b_hh_1f = (const float*)d_in[15];
  const float* w_ih_1b = (const float*)d_in[16];
  const float* w_hh_1b = (const float*)d_in[17];
  const float* b_ih_1b = (const float*)d_in[18];
  const float* b_hh_1b = (const float*)d_in[19];
  const float* w_lin   = (const float*)d_in[20];
  const float* b_lin   = (const float*)d_in[21];
  float* out = (float*)d_out;

  char* ws = (char*)d_ws;
  size_t off = 0;
  auto alloc = [&](size_t bytes) -> char* {
    char* p = ws + off;
    off += (bytes + 255) & ~(size_t)255;
    return p;
  };
  _Float16* xbf   = (_Float16*)alloc((size_t)T_ * 320 * 2);        // 21 MB
  _Float16* h1bf  = (_Float16*)alloc((size_t)T_ * 512 * 2);        // 33.5 MB
  _Float16* gx    = (_Float16*)alloc((size_t)2 * T_ * G4H * 2);    // 134 MB
  _Float16* Bt0   = (_Float16*)alloc((size_t)2048 * 320 * 2);
  _Float16* Bt1   = (_Float16*)alloc((size_t)2048 * 512 * 2);
  _Float16* Wr0   = (_Float16*)alloc((size_t)2 * G4H * H_ * 2);
  _Float16* Wr1   = (_Float16*)alloc((size_t)2 * G4H * H_ * 2);
  float*    bias0 = (float*)alloc(2048 * 4);
  float*    bias1 = (float*)alloc(2048 * 4);
  float*    pd2   = (float*)alloc((size_t)2 * B_ * S_ * 4);        // 256 KB

  // opt-in to 147 KB dynamic LDS for the single-block-chain kernels
  // (host-side attribute set, not a stream op -- graph-capture safe)
  (void)hipFuncSetAttribute(reinterpret_cast<const void*>(&k_rec<0>),
                            hipFuncAttributeMaxDynamicSharedMemorySize, 150528);
  (void)hipFuncSetAttribute(reinterpret_cast<const void*>(&k_rec<1>),
                            hipFuncAttributeMaxDynamicSharedMemorySize, 150528);

  // prep
  k_prep_wih<<<(2048 * 320) / 256, 256, 0, stream>>>(w_ih_0f, w_ih_0b, Bt0, 300, 320, 2048 * 320);
  k_prep_wih<<<(2048 * 512) / 256, 256, 0, stream>>>(w_ih_1f, w_ih_1b, Bt1, 512, 512, 2048 * 512);
  k_prep_whh<<<524288 / 256, 256, 0, stream>>>(w_hh_0f, w_hh_0b, Wr0);
  k_prep_whh<<<524288 / 256, 256, 0, stream>>>(w_hh_1f, w_hh_1b, Wr1);
  k_prep_bias<<<8, 256, 0, stream>>>(b_ih_0f, b_hh_0f, b_ih_0b, b_hh_0b, bias0);
  k_prep_bias<<<8, 256, 0, stream>>>(b_ih_1f, b_hh_1f, b_ih_1b, b_hh_1b, bias1);
  k_gather<<<(T_ * 40) / 256, 256, 0, stream>>>(ids, emb, xbf);

  hipMemsetAsync(pd2, 0, (size_t)2 * B_ * S_ * 4, stream);
  hipMemsetAsync((char*)d_out + (size_t)T_ * 4, 0, 4, stream);

  // layer 0
  k_gemm<320><<<dim3(16, 256), 256, 0, stream>>>(xbf, Bt0, bias0, gx);
  k_rec<0><<<8, 512, 150528, stream>>>(gx, Wr0, h1bf, pd2, w_lin);

  // layer 1
  k_gemm<512><<<dim3(16, 256), 256, 0, stream>>>(h1bf, Bt1, bias1, gx);
  k_rec<1><<<8, 512, 150528, stream>>>(gx, Wr1, h1bf, pd2, w_lin);

  k_final<<<64, 256, 0, stream>>>(pd2, labels, masks, b_lin, out);
}

// Round 11
// 5335.482 us; speedup vs baseline: 1.0433x; 1.0433x over previous
//
#include <hip/hip_runtime.h>
#include <hip/hip_bf16.h>
#include <stdint.h>

// Problem constants
#define B_  64
#define S_  512
#define E_  300
#define H_  256
#define T_  (B_*S_)     // 32768 tokens
#define G4H 1024        // 4*H gate rows per direction

using half8  = __attribute__((ext_vector_type(8))) _Float16;
using half4  = __attribute__((ext_vector_type(4))) _Float16;
using float4v = __attribute__((ext_vector_type(4))) float;

__device__ inline float sigm(float x) { return 1.f / (1.f + __expf(-x)); }
__device__ inline float tanhf_(float x) {
  float cx = fminf(fmaxf(x, -15.f), 15.f);
  float e = __expf(2.f * cx);
  return (e - 1.f) / (e + 1.f);
}

// raw barrier: drains LDS only, keeps global loads/stores in flight
#define BARRIER() asm volatile("s_waitcnt lgkmcnt(0)\n\ts_barrier" ::: "memory")

// Un-rematerializable 16B load WITH wait: spill-safe under any register
// pressure (the value is defined before the asm ends). r10's issue-only
// variant caused in-flight-destination spills -> register corruption -> GPU
// fault. Init cost (~48 serialized loads) is one-time, ~15us.
__device__ inline uint4 ldx4_pin(const _Float16* p) {
  uint4 r;
  asm volatile("global_load_dwordx4 %0, %1, off\n\ts_waitcnt vmcnt(0)"
               : "=v"(r) : "v"(p));
  return r;
}

// ---------------------------------------------------------------------------
// Prep kernels (unchanged)
// ---------------------------------------------------------------------------
__global__ __launch_bounds__(256) void k_prep_wih(const float* __restrict__ wf,
    const float* __restrict__ wb, _Float16* __restrict__ Bt,
    int KIN, int KP, int total)
{
  int idx = blockIdx.x * 256 + threadIdx.x;
  if (idx >= total) return;
  int n = idx / KP, k = idx % KP;
  int dd = n >> 10, nn = n & 1023;
  int row = (nn & 3) * 256 + (nn >> 2);
  const float* src = dd ? wb : wf;
  Bt[idx] = (_Float16)(k < KIN ? src[row * KIN + k] : 0.f);
}

__global__ __launch_bounds__(256) void k_prep_whh(const float* __restrict__ wf,
    const float* __restrict__ wb, _Float16* __restrict__ Wr)
{
  int idx = blockIdx.x * 256 + threadIdx.x;     // 0 .. 2*1024*256-1
  int dd = idx >> 18;
  int rem = idx & 262143;
  int n = rem >> 8, k = rem & 255;
  int row = (n & 3) * 256 + (n >> 2);
  Wr[idx] = (_Float16)((dd ? wb : wf)[row * 256 + k]);
}

__global__ void k_prep_bias(const float* __restrict__ bif, const float* __restrict__ bhf,
    const float* __restrict__ bib, const float* __restrict__ bhb, float* __restrict__ bias)
{
  int n = blockIdx.x * 256 + threadIdx.x;       // 0..2047
  int dd = n >> 10, nn = n & 1023;
  int row = (nn & 3) * 256 + (nn >> 2);
  bias[n] = dd ? (bib[row] + bhb[row]) : (bif[row] + bhf[row]);
}

__global__ __launch_bounds__(256) void k_gather(const int* __restrict__ ids,
    const float* __restrict__ emb, _Float16* __restrict__ xbf)
{
  int idx = blockIdx.x * 256 + threadIdx.x;     // T*40 threads, 8 f16 each
  int tt = idx / 40;
  int ch = idx % 40;
  int b = tt & 63, s = tt >> 6;
  int id = ids[b * S_ + s];
  const float* src = emb + (size_t)id * E_ + ch * 8;
  half8 v;
#pragma unroll
  for (int e = 0; e < 8; ++e) {
    int k = ch * 8 + e;
    v[e] = (_Float16)(k < E_ ? src[e] : 0.f);
  }
  *(half8*)(xbf + (size_t)tt * 320 + ch * 8) = v;
}

// ---------------------------------------------------------------------------
// Projection GEMM (unchanged): gx[d][t][b][n'] = A @ Bt^T + bias
// ---------------------------------------------------------------------------
template<int K>
__global__ __launch_bounds__(256) void k_gemm(const _Float16* __restrict__ A,
    const _Float16* __restrict__ Bt, const float* __restrict__ bias,
    _Float16* __restrict__ gx)
{
  __shared__ _Float16 sA[128 * 72];
  __shared__ _Float16 sB[128 * 72];
  const int tid = threadIdx.x;
  const int t0 = blockIdx.y * 128;
  const int n0 = blockIdx.x * 128;
  const int lane = tid & 63, wid = tid >> 6;
  const int l15 = lane & 15, q = lane >> 4;
  const int wm = wid & 1, wn = wid >> 1;

  float4v acc[4][4] = {};

  for (int kt = 0; kt < K / 64; ++kt) {
    __syncthreads();
#pragma unroll
    for (int c = 0; c < 4; ++c) {
      int f = tid * 4 + c;
      int row = f >> 3, seg = f & 7;
      *(half8*)&sA[row * 72 + seg * 8] =
          *(const half8*)(A + (size_t)(t0 + row) * K + kt * 64 + seg * 8);
      *(half8*)&sB[row * 72 + seg * 8] =
          *(const half8*)(Bt + (size_t)(n0 + row) * K + kt * 64 + seg * 8);
    }
    __syncthreads();
#pragma unroll
    for (int kk = 0; kk < 2; ++kk) {
      half8 a[4], b[4];
#pragma unroll
      for (int mt = 0; mt < 4; ++mt)
        a[mt] = *(const half8*)&sA[(wm * 64 + mt * 16 + l15) * 72 + kk * 32 + q * 8];
#pragma unroll
      for (int nt = 0; nt < 4; ++nt)
        b[nt] = *(const half8*)&sB[(wn * 64 + nt * 16 + l15) * 72 + kk * 32 + q * 8];
#pragma unroll
      for (int mt = 0; mt < 4; ++mt)
#pragma unroll
        for (int nt = 0; nt < 4; ++nt)
          acc[mt][nt] = __builtin_amdgcn_mfma_f32_16x16x32_f16(a[mt], b[nt], acc[mt][nt], 0, 0, 0);
    }
  }

#pragma unroll
  for (int mt = 0; mt < 4; ++mt) {
#pragma unroll
    for (int nt = 0; nt < 4; ++nt) {
      int token = t0 + wm * 64 + mt * 16 + q * 4;
      int n = n0 + wn * 64 + nt * 16 + l15;
      float bs = bias[n];
      size_t base = (size_t)(n >> 10) * ((size_t)T_ * G4H) + (size_t)token * G4H + (n & 1023);
#pragma unroll
      for (int r = 0; r < 4; ++r)
        gx[base + (size_t)r * G4H] = (_Float16)(acc[mt][nt][r] + bs);
    }
  }
}

// ---------------------------------------------------------------------------
// Persistent recurrence: SINGLE-BLOCK CHAINS v3.
// r9/r10 post-mortems: both failures trace to the allocator budgeting 128
// arch VGPRs while the design needs ~248 of the 256 unified regs available
// at 2 waves/SIMD. v3 communicates the budget directly:
//   amdgpu_flat_work_group_size(512,512) + amdgpu_waves_per_eu(2,2)
//   -> register budget = 512-reg file / 2 waves = 256 unified regs/wave.
// Demand: 6 weight tiles x 8 kt x uint4 = 192 + acc[4]=16 + gq[4]=8 +
// creg[8]=8 + temps ~24 = ~248 <= 256. Weight init is wait-per-load
// (spill-safe; r10's issue-only variant corrupted registers -> GPU fault).
// Structure otherwise = r10: 2-pass step (acc[4]/pass), gq reused across
// passes, hst stride 264 halfs (528B = 2 lanes/bank, conflict-free).
// ---------------------------------------------------------------------------
template<int LAYER>
__global__
__attribute__((amdgpu_flat_work_group_size(512, 512)))
__attribute__((amdgpu_waves_per_eu(2, 2)))
void k_rec(const _Float16* __restrict__ gx,
    const _Float16* __restrict__ Wr, _Float16* __restrict__ h1bf,
    float* __restrict__ pd2, const float* __restrict__ w_lin)
{
  extern __shared__ char smem[];
  _Float16* wlds = (_Float16*)smem;                     // 128 KB swizzled W tiles 6,7
  _Float16* hst  = (_Float16*)(smem + 131072);          // [2][16][264] = 16896 B
  float*    wls  = (float*)(smem + 131072 + 16896);     // [256], 1 KB

  const int tid = threadIdx.x;
  const int cg = blockIdx.x;                  // chain 0..7
  const int d = cg >> 2, g = cg & 3;
  const int wv = tid >> 6, lane = tid & 63;
  const int l15 = lane & 15, q = lane >> 4;
  const int bglob = g * 16 + l15;             // this thread's batch row

  if (tid < 256) wls[tid] = w_lin[tid];
  for (int i = tid; i < 4224; i += 512)       // zero both hst buffers (dwords)
    ((uint32_t*)hst)[i] = 0u;

  // ---- weights: wave wv owns gate rows [wv*128, wv*128+128) ----
  // tiles 0..5 -> registers (wait-per-load, spill-safe); 6,7 -> swizzled LDS
  uint4 wreg[6][8];
#pragma unroll
  for (int nt = 0; nt < 6; ++nt)
#pragma unroll
    for (int kt = 0; kt < 8; ++kt)
      wreg[nt][kt] = ldx4_pin(Wr +
          (size_t)(d * G4H + wv * 128 + nt * 16 + l15) * H_ + kt * 32 + q * 8);

#pragma unroll
  for (int tt = 0; tt < 2; ++tt)
#pragma unroll
    for (int j = 0; j < 8; ++j) {
      int row = wv * 128 + (6 + tt) * 16 + l15;
      uint4 w = *(const uint4*)(Wr + (size_t)(d * G4H + row) * H_ + q * 64 + j * 8);
      int byo = (q * 128 + j * 16) ^ ((l15 & 7) << 4);   // swizzled byte offset in row
      *(uint4*)(wlds + wv * 8192 + tt * 4096 + l15 * 256 + (byo >> 1)) = w;
    }

  float creg[8] = {};                         // c-state: 8 cells/thread (f32)
  uint2 gq[4];                                // gx quads, REUSED across passes

  // prime gq with step-0 pass-0 quads
  {
    const int time0 = d ? (S_ - 1) : 0;
    const _Float16* gp = gx + ((size_t)d * T_ + (size_t)time0 * B_ + bglob) * G4H
                           + wv * 128 + q * 4;
#pragma unroll
    for (int i = 0; i < 4; ++i)
      gq[i] = *(const uint2*)(gp + i * 16);
  }
  __syncthreads();

  for (int t = 0; t < S_; ++t) {
    const int time = d ? (S_ - 1 - t) : t;
    const int cur = t & 1, nxt = cur ^ 1;
    const int tn = (t + 1 < S_) ? t + 1 : t;
    const int timen = d ? (S_ - 1 - tn) : tn;
    const _Float16* gp0 = gx + ((size_t)d * T_ + (size_t)time * B_ + bglob) * G4H
                            + wv * 128 + q * 4;
    const _Float16* gpn = gx + ((size_t)d * T_ + (size_t)timen * B_ + bglob) * G4H
                            + wv * 128 + q * 4;
    float partial = 0.f;

#pragma unroll
    for (int pass = 0; pass < 2; ++pass) {
      // acc init from gq (gates i,f,g,o of 4 cells)
      float4v acc[4];
#pragma unroll
      for (int i = 0; i < 4; ++i) {
        half4 hz = __builtin_bit_cast(half4, gq[i]);
        acc[i][0] = (float)hz[0];
        acc[i][1] = (float)hz[1];
        acc[i][2] = (float)hz[2];
        acc[i][3] = (float)hz[3];
      }
      // re-issue gq: pass0 -> this step's pass-1 quads; pass1 -> next step's
      // pass-0 quads. Covered by >= one pass of compute before consumption.
      {
        const _Float16* gsrc = (pass == 0) ? (gp0 + 64) : gpn;
#pragma unroll
        for (int i = 0; i < 4; ++i)
          gq[i] = *(const uint2*)(gsrc + i * 16);
      }

      // MFMA: 4 tiles x 8 kt, swapped operands (W as A, h as B)
      if (pass == 0) {
#pragma unroll
        for (int kt = 0; kt < 8; ++kt) {
          half8 hf = *(const half8*)(hst + cur * 4224 + l15 * 264 + kt * 32 + q * 8);
#pragma unroll
          for (int i = 0; i < 4; ++i)
            acc[i] = __builtin_amdgcn_mfma_f32_16x16x32_f16(
                __builtin_bit_cast(half8, wreg[i][kt]), hf, acc[i], 0, 0, 0);
        }
      } else {
#pragma unroll
        for (int kt = 0; kt < 8; ++kt) {
          half8 hf = *(const half8*)(hst + cur * 4224 + l15 * 264 + kt * 32 + q * 8);
          int byr = (kt * 64 + q * 16) ^ ((l15 & 7) << 4);
          half8 w6 = *(const half8*)(wlds + wv * 8192 + l15 * 256 + (byr >> 1));
          half8 w7 = *(const half8*)(wlds + wv * 8192 + 4096 + l15 * 256 + (byr >> 1));
          acc[0] = __builtin_amdgcn_mfma_f32_16x16x32_f16(
              __builtin_bit_cast(half8, wreg[4][kt]), hf, acc[0], 0, 0, 0);
          acc[1] = __builtin_amdgcn_mfma_f32_16x16x32_f16(
              __builtin_bit_cast(half8, wreg[5][kt]), hf, acc[1], 0, 0, 0);
          acc[2] = __builtin_amdgcn_mfma_f32_16x16x32_f16(w6, hf, acc[2], 0, 0, 0);
          acc[3] = __builtin_amdgcn_mfma_f32_16x16x32_f16(w7, hf, acc[3], 0, 0, 0);
        }
      }

      // epilogue for this pass's 4 cells, straight from acc
#pragma unroll
      for (int i = 0; i < 4; ++i) {
        const int nt = pass * 4 + i;
        const int cell = wv * 32 + nt * 4 + q;
        float cv = sigm(acc[i][1]) * creg[nt] + sigm(acc[i][0]) * tanhf_(acc[i][2]);
        float hv = sigm(acc[i][3]) * tanhf_(cv);
        creg[nt] = cv;
        _Float16 hf16 = (_Float16)hv;
        hst[nxt * 4224 + l15 * 264 + cell] = hf16;
        if (LAYER == 0)
          h1bf[((size_t)time * B_ + bglob) * 512 + d * H_ + cell] = hf16;
        else
          partial += 0.5f * hv * wls[cell];
      }
    }

    if (LAYER == 1) {
      partial += __shfl_xor(partial, 16);
      partial += __shfl_xor(partial, 32);
      if (q == 0)
        atomicAdd(pd2 + ((size_t)d * B_ + bglob) * S_ + time, partial);
    }

    BARRIER();   // release hst[nxt]; gq loads + output stores ride
  }
}

// scores + masked-MSE loss
__global__ __launch_bounds__(256) void k_final(const float* __restrict__ pd2,
    const float* __restrict__ labels, const int* __restrict__ masks,
    const float* __restrict__ b_lin, float* __restrict__ out)
{
  int b = blockIdx.x;
  int tid = threadIdx.x;
  float bl = b_lin[0];
  float se = 0.f, sm = 0.f;
  for (int s = tid; s < S_; s += 256) {
    float p = pd2[(size_t)b * S_ + s] + pd2[(size_t)(B_ + b) * S_ + s];
    float sc = sigm(p + bl);
    out[b * S_ + s] = sc;
    float m = (float)masks[b * S_ + s];
    float e = sc - labels[b * S_ + s];
    se += e * e * m;
    sm += m;
  }
  for (int off = 1; off < 64; off <<= 1) {
    se += __shfl_xor(se, off);
    sm += __shfl_xor(sm, off);
  }
  __shared__ float rs[4], rm[4];
  int wid = tid >> 6;
  if ((tid & 63) == 0) { rs[wid] = se; rm[wid] = sm; }
  __syncthreads();
  if (tid == 0) {
    float te = 0.f, tm = 0.f;
    for (int w = 0; w < 4; ++w) { te += rs[w]; tm += rm[w]; }
    atomicAdd(out + T_, (te / tm) * (1.f / 64.f));
  }
}

// ---------------------------------------------------------------------------
extern "C" void kernel_launch(void* const* d_in, const int* in_sizes, int n_in,
                              void* d_out, int out_size, void* d_ws, size_t ws_size,
                              hipStream_t stream)
{
  (void)in_sizes; (void)n_in; (void)out_size; (void)ws_size;
  const int*   ids    = (const int*)d_in[0];
  const float* labels = (const float*)d_in[1];
  const int*   masks  = (const int*)d_in[2];
  const float* emb    = (const float*)d_in[3];
  const float* w_ih_0f = (const float*)d_in[4];
  const float* w_hh_0f = (const float*)d_in[5];
  const float* b_ih_0f = (const float*)d_in[6];
  const float* b_hh_0f = (const float*)d_in[7];
  const float* w_ih_0b = (const float*)d_in[8];
  const float* w_hh_0b = (const float*)d_in[9];
  const float* b_ih_0b = (const float*)d_in[10];
  const float* b_hh_0b = (const float*)d_in[11];
  const float* w_ih_1f = (const float*)d_in[12];
  const float* w_hh_1f = (const float*)d_in[13];
  const float* b_ih_1f = (const float*)d_in[14];
  const float* b_hh_1f = (const float*)d_in[15];
  const float* w_ih_1b = (const float*)d_in[16];
  const float* w_hh_1b = (const float*)d_in[17];
  const float* b_ih_1b = (const float*)d_in[18];
  const float* b_hh_1b = (const float*)d_in[19];
  const float* w_lin   = (const float*)d_in[20];
  const float* b_lin   = (const float*)d_in[21];
  float* out = (float*)d_out;

  char* ws = (char*)d_ws;
  size_t off = 0;
  auto alloc = [&](size_t bytes) -> char* {
    char* p = ws + off;
    off += (bytes + 255) & ~(size_t)255;
    return p;
  };
  _Float16* xbf   = (_Float16*)alloc((size_t)T_ * 320 * 2);        // 21 MB
  _Float16* h1bf  = (_Float16*)alloc((size_t)T_ * 512 * 2);        // 33.5 MB
  _Float16* gx    = (_Float16*)alloc((size_t)2 * T_ * G4H * 2);    // 134 MB
  _Float16* Bt0   = (_Float16*)alloc((size_t)2048 * 320 * 2);
  _Float16* Bt1   = (_Float16*)alloc((size_t)2048 * 512 * 2);
  _Float16* Wr0   = (_Float16*)alloc((size_t)2 * G4H * H_ * 2);
  _Float16* Wr1   = (_Float16*)alloc((size_t)2 * G4H * H_ * 2);
  float*    bias0 = (float*)alloc(2048 * 4);
  float*    bias1 = (float*)alloc(2048 * 4);
  float*    pd2   = (float*)alloc((size_t)2 * B_ * S_ * 4);        // 256 KB

  // opt-in to 146 KB dynamic LDS for the single-block-chain kernels
  (void)hipFuncSetAttribute(reinterpret_cast<const void*>(&k_rec<0>),
                            hipFuncAttributeMaxDynamicSharedMemorySize, 148992);
  (void)hipFuncSetAttribute(reinterpret_cast<const void*>(&k_rec<1>),
                            hipFuncAttributeMaxDynamicSharedMemorySize, 148992);

  // prep
  k_prep_wih<<<(2048 * 320) / 256, 256, 0, stream>>>(w_ih_0f, w_ih_0b, Bt0, 300, 320, 2048 * 320);
  k_prep_wih<<<(2048 * 512) / 256, 256, 0, stream>>>(w_ih_1f, w_ih_1b, Bt1, 512, 512, 2048 * 512);
  k_prep_whh<<<524288 / 256, 256, 0, stream>>>(w_hh_0f, w_hh_0b, Wr0);
  k_prep_whh<<<524288 / 256, 256, 0, stream>>>(w_hh_1f, w_hh_1b, Wr1);
  k_prep_bias<<<8, 256, 0, stream>>>(b_ih_0f, b_hh_0f, b_ih_0b, b_hh_0b, bias0);
  k_prep_bias<<<8, 256, 0, stream>>>(b_ih_1f, b_hh_1f, b_ih_1b, b_hh_1b, bias1);
  k_gather<<<(T_ * 40) / 256, 256, 0, stream>>>(ids, emb, xbf);

  hipMemsetAsync(pd2, 0, (size_t)2 * B_ * S_ * 4, stream);
  hipMemsetAsync((char*)d_out + (size_t)T_ * 4, 0, 4, stream);

  // layer 0
  k_gemm<320><<<dim3(16, 256), 256, 0, stream>>>(xbf, Bt0, bias0, gx);
  k_rec<0><<<8, 512, 148992, stream>>>(gx, Wr0, h1bf, pd2, w_lin);

  // layer 1
  k_gemm<512><<<dim3(16, 256), 256, 0, stream>>>(h1bf, Bt1, bias1, gx);
  k_rec<1><<<8, 512, 148992, stream>>>(gx, Wr1, h1bf, pd2, w_lin);

  k_final<<<64, 256, 0, stream>>>(pd2, labels, masks, b_lin, out);
}

// Round 12
// 2855.547 us; speedup vs baseline: 1.9494x; 1.8685x over previous
//
#include <hip/hip_runtime.h>
#include <hip/hip_bf16.h>
#include <stdint.h>

// Problem constants
#define B_  64
#define S_  512
#define E_  300
#define H_  256
#define T_  (B_*S_)     // 32768 tokens
#define G4H 1024        // 4*H gate rows per direction

using half8  = __attribute__((ext_vector_type(8))) _Float16;
using half4  = __attribute__((ext_vector_type(4))) _Float16;
using float4v = __attribute__((ext_vector_type(4))) float;

union H2 { _Float16 h[2]; uint32_t u; };

__device__ inline float sigm(float x) { return 1.f / (1.f + __expf(-x)); }
__device__ inline float tanhf_(float x) {
  float cx = fminf(fmaxf(x, -15.f), 15.f);
  float e = __expf(2.f * cx);
  return (e - 1.f) / (e + 1.f);
}

// raw barrier: drains LDS only, keeps global loads/stores in flight
#define BARRIER() asm volatile("s_waitcnt lgkmcnt(0)\n\ts_barrier" ::: "memory")

// Device-channel batched exchange poll (r4-proven): 3x16B sc0 sc1 loads,
// ONE wait. This is the channel that delivers h across blocks.
__device__ inline void ld3_dev(const uint64_t* p0, const uint64_t* p1,
                               const uint64_t* p2, uint4& a, uint4& b, uint4& c) {
  asm volatile(
      "global_load_dwordx4 %0, %3, off sc0 sc1\n\t"
      "global_load_dwordx4 %1, %4, off sc0 sc1\n\t"
      "global_load_dwordx4 %2, %5, off sc0 sc1\n\t"
      "s_waitcnt vmcnt(0)"
      : "=&v"(a), "=&v"(b), "=&v"(c)
      : "v"(p0), "v"(p1), "v"(p2) : "memory");
}
// Un-rematerializable 16B load WITH wait (spill-safe weight residency)
__device__ inline uint4 ldx4_pin(const _Float16* p) {
  uint4 r;
  asm volatile("global_load_dwordx4 %0, %1, off\n\ts_waitcnt vmcnt(0)"
               : "=v"(r) : "v"(p));
  return r;
}

// ---------------------------------------------------------------------------
// Prep kernels (unchanged)
// ---------------------------------------------------------------------------
__global__ __launch_bounds__(256) void k_prep_wih(const float* __restrict__ wf,
    const float* __restrict__ wb, _Float16* __restrict__ Bt,
    int KIN, int KP, int total)
{
  int idx = blockIdx.x * 256 + threadIdx.x;
  if (idx >= total) return;
  int n = idx / KP, k = idx % KP;
  int dd = n >> 10, nn = n & 1023;
  int row = (nn & 3) * 256 + (nn >> 2);
  const float* src = dd ? wb : wf;
  Bt[idx] = (_Float16)(k < KIN ? src[row * KIN + k] : 0.f);
}

__global__ __launch_bounds__(256) void k_prep_whh(const float* __restrict__ wf,
    const float* __restrict__ wb, _Float16* __restrict__ Wr)
{
  int idx = blockIdx.x * 256 + threadIdx.x;     // 0 .. 2*1024*256-1
  int dd = idx >> 18;
  int rem = idx & 262143;
  int n = rem >> 8, k = rem & 255;
  int row = (n & 3) * 256 + (n >> 2);
  Wr[idx] = (_Float16)((dd ? wb : wf)[row * 256 + k]);
}

__global__ void k_prep_bias(const float* __restrict__ bif, const float* __restrict__ bhf,
    const float* __restrict__ bib, const float* __restrict__ bhb, float* __restrict__ bias)
{
  int n = blockIdx.x * 256 + threadIdx.x;       // 0..2047
  int dd = n >> 10, nn = n & 1023;
  int row = (nn & 3) * 256 + (nn >> 2);
  bias[n] = dd ? (bib[row] + bhb[row]) : (bif[row] + bhf[row]);
}

__global__ __launch_bounds__(256) void k_gather(const int* __restrict__ ids,
    const float* __restrict__ emb, _Float16* __restrict__ xbf)
{
  int idx = blockIdx.x * 256 + threadIdx.x;     // T*40 threads, 8 f16 each
  int tt = idx / 40;
  int ch = idx % 40;
  int b = tt & 63, s = tt >> 6;
  int id = ids[b * S_ + s];
  const float* src = emb + (size_t)id * E_ + ch * 8;
  half8 v;
#pragma unroll
  for (int e = 0; e < 8; ++e) {
    int k = ch * 8 + e;
    v[e] = (_Float16)(k < E_ ? src[e] : 0.f);
  }
  *(half8*)(xbf + (size_t)tt * 320 + ch * 8) = v;
}

// ---------------------------------------------------------------------------
// Projection GEMM (unchanged): gx[d][t][b][n'] = A @ Bt^T + bias
// ---------------------------------------------------------------------------
template<int K>
__global__ __launch_bounds__(256) void k_gemm(const _Float16* __restrict__ A,
    const _Float16* __restrict__ Bt, const float* __restrict__ bias,
    _Float16* __restrict__ gx)
{
  __shared__ _Float16 sA[128 * 72];
  __shared__ _Float16 sB[128 * 72];
  const int tid = threadIdx.x;
  const int t0 = blockIdx.y * 128;
  const int n0 = blockIdx.x * 128;
  const int lane = tid & 63, wid = tid >> 6;
  const int l15 = lane & 15, q = lane >> 4;
  const int wm = wid & 1, wn = wid >> 1;

  float4v acc[4][4] = {};

  for (int kt = 0; kt < K / 64; ++kt) {
    __syncthreads();
#pragma unroll
    for (int c = 0; c < 4; ++c) {
      int f = tid * 4 + c;
      int row = f >> 3, seg = f & 7;
      *(half8*)&sA[row * 72 + seg * 8] =
          *(const half8*)(A + (size_t)(t0 + row) * K + kt * 64 + seg * 8);
      *(half8*)&sB[row * 72 + seg * 8] =
          *(const half8*)(Bt + (size_t)(n0 + row) * K + kt * 64 + seg * 8);
    }
    __syncthreads();
#pragma unroll
    for (int kk = 0; kk < 2; ++kk) {
      half8 a[4], b[4];
#pragma unroll
      for (int mt = 0; mt < 4; ++mt)
        a[mt] = *(const half8*)&sA[(wm * 64 + mt * 16 + l15) * 72 + kk * 32 + q * 8];
#pragma unroll
      for (int nt = 0; nt < 4; ++nt)
        b[nt] = *(const half8*)&sB[(wn * 64 + nt * 16 + l15) * 72 + kk * 32 + q * 8];
#pragma unroll
      for (int mt = 0; mt < 4; ++mt)
#pragma unroll
        for (int nt = 0; nt < 4; ++nt)
          acc[mt][nt] = __builtin_amdgcn_mfma_f32_16x16x32_f16(a[mt], b[nt], acc[mt][nt], 0, 0, 0);
    }
  }

#pragma unroll
  for (int mt = 0; mt < 4; ++mt) {
#pragma unroll
    for (int nt = 0; nt < 4; ++nt) {
      int token = t0 + wm * 64 + mt * 16 + q * 4;
      int n = n0 + wn * 64 + nt * 16 + l15;
      float bs = bias[n];
      size_t base = (size_t)(n >> 10) * ((size_t)T_ * G4H) + (size_t)token * G4H + (n & 1023);
#pragma unroll
      for (int r = 0; r < 4; ++r)
        gx[base + (size_t)r * G4H] = (_Float16)(acc[mt][nt][r] + bs);
    }
  }
}

// ---------------------------------------------------------------------------
// Persistent recurrence: r4 winner structure (32 blocks, fan-in-4, device
// channel) + SWAPPED-OPERAND MFMA with permuted W rows (HW-verified r9/r11):
//   acc[nt] = mfma(W_tile, h): D row = q*4+r (gate r of a cell), col = l15
//   (batch). W tiles permuted so tile nt holds cells == nt (mod 4) of the
//   wave's 16-cell group -> thread (q,l15) owns 4 ADJACENT cells
//   rg*64+wv*16+4q+{0..3} with all 4 gates in acc[nt][0..3].
// Removes: preS staging (16.6KB LDS), the second BARRIER, preS bank
// conflicts, the epilogue LDS re-read. gx folds into the MFMA C-init.
// h staging: double-buffered [16][264] (264-half stride = conflict-free
// ds_read_b128; r4's 288 was a 2-way conflict). Publish channel layout
// byte-identical to r4 (adjacent j's per producer thread); publish now
// issues immediately after the per-thread epilogue -> earlier on the
// inter-chain critical path.
// ---------------------------------------------------------------------------
template<int LAYER>
__global__ __launch_bounds__(256, 1) void k_rec(const _Float16* __restrict__ gx,
    const _Float16* __restrict__ Wr, uint64_t* __restrict__ hx,
    _Float16* __restrict__ h1bf, float* __restrict__ pd2,
    const float* __restrict__ w_lin)
{
  __shared__ _Float16 hst[2][16 * 264];   // h [b 16][j 256], pad->264
  __shared__ float    wls[256];

  const int tid = threadIdx.x;
  const int role = blockIdx.x;                // 0..31
  const int cg = role >> 2, rg = role & 3;    // chain, quarter
  const int d = cg >> 2, g = cg & 3;
  const int lane = tid & 63, wv = tid >> 6;
  const int l15 = lane & 15, q = lane >> 4;
  const int bglob = g * 16 + l15;             // this thread's batch row

  if (tid < 256) wls[tid] = w_lin[tid];
  for (int i = tid; i < 2 * 16 * 132; i += 256)
    ((uint32_t*)&hst[0][0])[i] = 0u;

  // ---- W fragments, PERMUTED rows: D row i=q*4+r of tile nt must be the
  // W row of (cell-in-tile i>>2, gate i&3) where tile nt's cells are
  // {wv*16 + 4k + nt}. Fragment A-row index = l15 at load time =>
  // row(l15) = rg*256 + wv*64 + (l15>>2)*16 + nt*4 + (l15&3).
  uint4 wreg[4][8];
#pragma unroll
  for (int nt = 0; nt < 4; ++nt)
#pragma unroll
    for (int kt = 0; kt < 8; ++kt) {
      int row = rg * 256 + wv * 64 + (l15 >> 2) * 16 + nt * 4 + (l15 & 3);
      wreg[nt][kt] = ldx4_pin(Wr + (size_t)(d * G4H + row) * H_ + kt * 32 + q * 8);
    }

  float creg[4] = {0.f, 0.f, 0.f, 0.f};       // c-state: 4 cells/thread

  uint64_t* base = hx + (size_t)cg * 2 * 2048;
  const int off2 = tid * 2;
  const int q2a = (rg + 1) & 3, q2b = (rg + 2) & 3, q2c = (rg + 3) & 3;
  const int jloc = rg * 64 + wv * 16 + q * 4;   // this thread's 4 cells (abs j)

  // gx: 16 halfs = 4 gates x 4 owned cells, 2x16B loads
  uint4 gqa, gqb;
  {
    const int time0 = d ? (S_ - 1) : 0;
    const _Float16* gp = gx + ((size_t)d * T_ + (size_t)time0 * B_ + bglob) * G4H
                           + rg * 256 + wv * 64 + q * 16;
    gqa = *(const uint4*)(gp);
    gqb = *(const uint4*)(gp + 8);
  }
  __syncthreads();

  for (int t = 0; t < S_; ++t) {
    const int time = d ? (S_ - 1 - t) : t;
    const int cur = t & 1, nxt = cur ^ 1;

    if (t > 0) {
      const uint64_t* ss = base + (size_t)(t & 1) * 2048;
      const uint32_t tt = (uint32_t)t;
      uint32_t dat[6];
      unsigned pend = 0x3fu;
      for (;;) {
        uint4 A, Bv, C;
        ld3_dev(ss + q2a * 512 + off2, ss + q2b * 512 + off2,
                ss + q2c * 512 + off2, A, Bv, C);
        if ((pend & 1u)  && A.y  == tt) { dat[0] = A.x;  pend &= ~1u; }
        if ((pend & 2u)  && A.w  == tt) { dat[1] = A.z;  pend &= ~2u; }
        if ((pend & 4u)  && Bv.y == tt) { dat[2] = Bv.x; pend &= ~4u; }
        if ((pend & 8u)  && Bv.w == tt) { dat[3] = Bv.z; pend &= ~8u; }
        if ((pend & 16u) && C.y  == tt) { dat[4] = C.x;  pend &= ~16u; }
        if ((pend & 32u) && C.w  == tt) { dat[5] = C.z;  pend &= ~32u; }
        if (!pend) break;
      }
      const int sb = tid >> 4, jp = (tid & 15) * 2;
      uint32_t* hc = (uint32_t*)&hst[cur][0];
      uint2 va; va.x = dat[0]; va.y = dat[1];
      uint2 vb; vb.x = dat[2]; vb.y = dat[3];
      uint2 vc; vc.x = dat[4]; vc.y = dat[5];
      *(uint2*)&hc[sb * 132 + q2a * 32 + jp] = va;
      *(uint2*)&hc[sb * 132 + q2b * 32 + jp] = vb;
      *(uint2*)&hc[sb * 132 + q2c * 32 + jp] = vc;
    }
    BARRIER();   // hst[cur] complete (spin writes + prev-step own writes)

    // prefetch gx(t+1) into fresh regs; consumed at next step's acc-init
    uint4 gqa_n, gqb_n;
    {
      const int tn = (t + 1 < S_) ? t + 1 : t;
      const int timen = d ? (S_ - 1 - tn) : tn;
      const _Float16* gp = gx + ((size_t)d * T_ + (size_t)timen * B_ + bglob) * G4H
                             + rg * 256 + wv * 64 + q * 16;
      gqa_n = *(const uint4*)(gp);
      gqb_n = *(const uint4*)(gp + 8);
    }

    // acc init = gx (MFMA C-input)
    float4v acc[4];
    {
      half8 ga = __builtin_bit_cast(half8, gqa);
      half8 gb = __builtin_bit_cast(half8, gqb);
#pragma unroll
      for (int r = 0; r < 4; ++r) {
        acc[0][r] = (float)ga[r];
        acc[1][r] = (float)ga[4 + r];
        acc[2][r] = (float)gb[r];
        acc[3][r] = (float)gb[4 + r];
      }
    }

    // MFMA, swapped operands: pre[gates][batch] = W @ h(t)^T
#pragma unroll
    for (int kt = 0; kt < 8; ++kt) {
      half8 hf = *(const half8*)&hst[cur][l15 * 264 + kt * 32 + q * 8];
#pragma unroll
      for (int nt = 0; nt < 4; ++nt)
        acc[nt] = __builtin_amdgcn_mfma_f32_16x16x32_f16(
            __builtin_bit_cast(half8, wreg[nt][kt]), hf, acc[nt], 0, 0, 0);
    }

    // epilogue straight from acc: 4 cells (adjacent j), gates in acc[nt][r]
    half4 hv4;
    float partial = 0.f;
#pragma unroll
    for (int nt = 0; nt < 4; ++nt) {
      float cv = sigm(acc[nt][1]) * creg[nt] + sigm(acc[nt][0]) * tanhf_(acc[nt][2]);
      float hv = sigm(acc[nt][3]) * tanhf_(cv);
      creg[nt] = cv;
      hv4[nt] = (_Float16)hv;
      if (LAYER == 1) partial += 0.5f * hv * wls[jloc + nt];
    }

    // publish FIRST (earliest point h(t+1) exists): channel layout == r4
    {
      H2 p0; p0.h[0] = hv4[0]; p0.h[1] = hv4[1];
      H2 p1; p1.h[0] = hv4[2]; p1.h[1] = hv4[3];
      uint32_t tg = (uint32_t)(t + 1);
      uint64_t w0 = ((uint64_t)tg << 32) | p0.u;
      uint64_t w1 = ((uint64_t)tg << 32) | p1.u;
      uint64_t* sd = base + (size_t)((t + 1) & 1) * 2048 + rg * 512
                   + l15 * 32 + wv * 8 + q * 2;
      __hip_atomic_store(sd + 0, w0, __ATOMIC_RELAXED, __HIP_MEMORY_SCOPE_AGENT);
      __hip_atomic_store(sd + 1, w1, __ATOMIC_RELAXED, __HIP_MEMORY_SCOPE_AGENT);
    }

    // own-quarter h(t+1) into the next LDS buffer (read next step)
    *(half4*)&hst[nxt][l15 * 264 + jloc] = hv4;

    if (LAYER == 0) {
      *(half4*)(h1bf + ((size_t)time * B_ + bglob) * 512 + d * H_ + jloc) = hv4;
    } else {
      partial += __shfl_xor(partial, 16);
      partial += __shfl_xor(partial, 32);
      if (q == 0)
        atomicAdd(pd2 + ((size_t)d * B_ + bglob) * S_ + time, partial);
    }

    gqa = gqa_n; gqb = gqb_n;
  }
}

// scores + masked-MSE loss
__global__ __launch_bounds__(256) void k_final(const float* __restrict__ pd2,
    const float* __restrict__ labels, const int* __restrict__ masks,
    const float* __restrict__ b_lin, float* __restrict__ out)
{
  int b = blockIdx.x;
  int tid = threadIdx.x;
  float bl = b_lin[0];
  float se = 0.f, sm = 0.f;
  for (int s = tid; s < S_; s += 256) {
    float p = pd2[(size_t)b * S_ + s] + pd2[(size_t)(B_ + b) * S_ + s];
    float sc = sigm(p + bl);
    out[b * S_ + s] = sc;
    float m = (float)masks[b * S_ + s];
    float e = sc - labels[b * S_ + s];
    se += e * e * m;
    sm += m;
  }
  for (int off = 1; off < 64; off <<= 1) {
    se += __shfl_xor(se, off);
    sm += __shfl_xor(sm, off);
  }
  __shared__ float rs[4], rm[4];
  int wid = tid >> 6;
  if ((tid & 63) == 0) { rs[wid] = se; rm[wid] = sm; }
  __syncthreads();
  if (tid == 0) {
    float te = 0.f, tm = 0.f;
    for (int w = 0; w < 4; ++w) { te += rs[w]; tm += rm[w]; }
    atomicAdd(out + T_, (te / tm) * (1.f / 64.f));
  }
}

// ---------------------------------------------------------------------------
extern "C" void kernel_launch(void* const* d_in, const int* in_sizes, int n_in,
                              void* d_out, int out_size, void* d_ws, size_t ws_size,
                              hipStream_t stream)
{
  (void)in_sizes; (void)n_in; (void)out_size; (void)ws_size;
  const int*   ids    = (const int*)d_in[0];
  const float* labels = (const float*)d_in[1];
  const int*   masks  = (const int*)d_in[2];
  const float* emb    = (const float*)d_in[3];
  const float* w_ih_0f = (const float*)d_in[4];
  const float* w_hh_0f = (const float*)d_in[5];
  const float* b_ih_0f = (const float*)d_in[6];
  const float* b_hh_0f = (const float*)d_in[7];
  const float* w_ih_0b = (const float*)d_in[8];
  const float* w_hh_0b = (const float*)d_in[9];
  const float* b_ih_0b = (const float*)d_in[10];
  const float* b_hh_0b = (const float*)d_in[11];
  const float* w_ih_1f = (const float*)d_in[12];
  const float* w_hh_1f = (const float*)d_in[13];
  const float* b_ih_1f = (const float*)d_in[14];
  const float* b_hh_1f = (const float*)d_in[15];
  const float* w_ih_1b = (const float*)d_in[16];
  const float* w_hh_1b = (const float*)d_in[17];
  const float* b_ih_1b = (const float*)d_in[18];
  const float* b_hh_1b = (const float*)d_in[19];
  const float* w_lin   = (const float*)d_in[20];
  const float* b_lin   = (const float*)d_in[21];
  float* out = (float*)d_out;

  char* ws = (char*)d_ws;
  size_t off = 0;
  auto alloc = [&](size_t bytes) -> char* {
    char* p = ws + off;
    off += (bytes + 255) & ~(size_t)255;
    return p;
  };
  _Float16* xbf   = (_Float16*)alloc((size_t)T_ * 320 * 2);        // 21 MB
  _Float16* h1bf  = (_Float16*)alloc((size_t)T_ * 512 * 2);        // 33.5 MB
  _Float16* gx    = (_Float16*)alloc((size_t)2 * T_ * G4H * 2);    // 134 MB
  _Float16* Bt0   = (_Float16*)alloc((size_t)2048 * 320 * 2);
  _Float16* Bt1   = (_Float16*)alloc((size_t)2048 * 512 * 2);
  _Float16* Wr0   = (_Float16*)alloc((size_t)2 * G4H * H_ * 2);
  _Float16* Wr1   = (_Float16*)alloc((size_t)2 * G4H * H_ * 2);
  float*    bias0 = (float*)alloc(2048 * 4);
  float*    bias1 = (float*)alloc(2048 * 4);
  uint64_t* hx0   = (uint64_t*)alloc((size_t)8 * 2 * 2048 * 8);    // 256 KB
  uint64_t* hx1   = (uint64_t*)alloc((size_t)8 * 2 * 2048 * 8);
  float*    pd2   = (float*)alloc((size_t)2 * B_ * S_ * 4);        // 256 KB

  // prep
  k_prep_wih<<<(2048 * 320) / 256, 256, 0, stream>>>(w_ih_0f, w_ih_0b, Bt0, 300, 320, 2048 * 320);
  k_prep_wih<<<(2048 * 512) / 256, 256, 0, stream>>>(w_ih_1f, w_ih_1b, Bt1, 512, 512, 2048 * 512);
  k_prep_whh<<<524288 / 256, 256, 0, stream>>>(w_hh_0f, w_hh_0b, Wr0);
  k_prep_whh<<<524288 / 256, 256, 0, stream>>>(w_hh_1f, w_hh_1b, Wr1);
  k_prep_bias<<<8, 256, 0, stream>>>(b_ih_0f, b_hh_0f, b_ih_0b, b_hh_0b, bias0);
  k_prep_bias<<<8, 256, 0, stream>>>(b_ih_1f, b_hh_1f, b_ih_1b, b_hh_1b, bias1);
  k_gather<<<(T_ * 40) / 256, 256, 0, stream>>>(ids, emb, xbf);

  hipMemsetAsync(hx0, 0, (size_t)8 * 2 * 2048 * 8, stream);
  hipMemsetAsync(hx1, 0, (size_t)8 * 2 * 2048 * 8, stream);
  hipMemsetAsync(pd2, 0, (size_t)2 * B_ * S_ * 4, stream);
  hipMemsetAsync((char*)d_out + (size_t)T_ * 4, 0, 4, stream);

  // layer 0
  k_gemm<320><<<dim3(16, 256), 256, 0, stream>>>(xbf, Bt0, bias0, gx);
  k_rec<0><<<32, 256, 0, stream>>>(gx, Wr0, hx0, h1bf, pd2, w_lin);

  // layer 1
  k_gemm<512><<<dim3(16, 256), 256, 0, stream>>>(h1bf, Bt1, bias1, gx);
  k_rec<1><<<32, 256, 0, stream>>>(gx, Wr1, hx1, h1bf, pd2, w_lin);

  k_final<<<64, 256, 0, stream>>>(pd2, labels, masks, b_lin, out);
}